// Round 1
// baseline (133.265 us; speedup 1.0000x reference)
//
#include <hip/hip_runtime.h>
#include <stdint.h>

typedef __bf16 bf16_t;
typedef bf16_t __attribute__((ext_vector_type(8))) bf16x8;
typedef float __attribute__((ext_vector_type(4))) f32x4;

#define BATCH 4
#define SEQ 1024
#define HIDD 1024
#define NH 16
#define DH 64

// ---------- helpers ----------
__device__ __forceinline__ unsigned short f2bf(float f) {
  unsigned u = __float_as_uint(f);
  u += 0x7fffu + ((u >> 16) & 1u);   // RNE (no NaN handling needed here)
  return (unsigned short)(u >> 16);
}

__device__ __forceinline__ f32x4 mfma16(bf16x8 a, bf16x8 b, f32x4 c) {
  return __builtin_amdgcn_mfma_f32_16x16x32_bf16(a, b, c, 0, 0, 0);
}

__device__ __forceinline__ void gload_lds16(const void* g, void* l) {
  __builtin_amdgcn_global_load_lds(
      (__attribute__((address_space(1))) void*)(uintptr_t)g,
      (__attribute__((address_space(3))) void*)l, 16, 0, 0);
}

// ---------- kernel 1: hidden_states fp32 -> bf16 ----------
__global__ void hs2bf(const float* __restrict__ x, unsigned short* __restrict__ y) {
  const int i = blockIdx.x * 256 + threadIdx.x;   // 1M float4s total
  const float4 f = ((const float4*)x)[i];
  ushort4 o = make_ushort4(f2bf(f.x), f2bf(f.y), f2bf(f.z), f2bf(f.w));
  ((ushort4*)y)[i] = o;
}

// ---------- kernel 2: W (K x N) fp32 -> Wt (N x K) bf16, for q/k/v ----------
__global__ __launch_bounds__(256) void wtrans(
    const float* __restrict__ Wq, const float* __restrict__ Wk,
    const float* __restrict__ Wv, unsigned short* __restrict__ Wt) {
  __shared__ unsigned short tile[64][72];  // +8 pad
  const int z = blockIdx.z;
  const float* W = (z == 0) ? Wq : (z == 1) ? Wk : Wv;
  unsigned short* o = Wt + (size_t)z * (1024 * 1024);
  const int k0 = blockIdx.x * 64, n0 = blockIdx.y * 64;
  const int r = threadIdx.x >> 6, c = threadIdx.x & 63;
#pragma unroll
  for (int i = 0; i < 16; ++i) {
    const int row = i * 4 + r;
    tile[row][c] = f2bf(W[(size_t)(k0 + row) * 1024 + n0 + c]);
  }
  __syncthreads();
#pragma unroll
  for (int i = 0; i < 16; ++i) {
    const int row = i * 4 + r;                 // row in n
    o[(size_t)(n0 + row) * 1024 + k0 + c] = tile[c][row];
  }
}

// ---------- kernel 3: QKV projection GEMM (m97-style gemm_bt) ----------
// C[m][n] = sum_k A[m][k] * Bt[n][k]; out = (C + bias) * scale, bf16.
__global__ __launch_bounds__(256) void qkv_gemm(
    const unsigned short* __restrict__ A,    // 4096 x 1024 bf16
    const unsigned short* __restrict__ Wt,   // 3 x (1024 x 1024) bf16, n-major
    const float* __restrict__ bq, const float* __restrict__ bk,
    const float* __restrict__ bv,
    unsigned short* __restrict__ outb) {     // 3 x (4096 x 1024) bf16
  __shared__ alignas(16) unsigned short Alds[128 * 32];
  __shared__ alignas(16) unsigned short Blds[128 * 32];

  const int z = blockIdx.z;
  const unsigned short* Bt = Wt + (size_t)z * (1024 * 1024);
  const float* bias = (z == 0) ? bq : (z == 1) ? bk : bv;
  unsigned short* outp = outb + (size_t)z * (4096 * 1024);
  const float scale = (z == 0) ? 0.125f : 1.0f;   // 1/sqrt(64) folded into Q

  const int m0 = blockIdx.x * 128;
  const int n0 = blockIdx.y * 128;
  const int t = threadIdx.x;
  const int w = t >> 6, l = t & 63;
  const int lg = l >> 4, lc = l & 15;
  const int wr = w >> 1, wc = w & 1;

  f32x4 acc[4][4] = {};

  for (int kt = 0; kt < 1024; kt += 32) {
    __syncthreads();
#pragma unroll
    for (int i = 0; i < 2; ++i) {
      const int c = i * 256 + t;          // 16B chunk id, 512 per tile
      const int row = c >> 2;
      const int kp = (c & 3) * 8;
      gload_lds16(A + (size_t)(m0 + row) * 1024 + kt + kp,
                  (char*)Alds + i * 4096 + w * 1024);
      gload_lds16(Bt + (size_t)(n0 + row) * 1024 + kt + kp,
                  (char*)Blds + i * 4096 + w * 1024);
    }
    __syncthreads();

    bf16x8 af[4], bfr[4];
#pragma unroll
    for (int m = 0; m < 4; ++m)
      af[m] = *(const bf16x8*)(Alds + (wr * 64 + m * 16 + lc) * 32 + lg * 8);
#pragma unroll
    for (int n = 0; n < 4; ++n)
      bfr[n] = *(const bf16x8*)(Blds + (wc * 64 + n * 16 + lc) * 32 + lg * 8);
#pragma unroll
    for (int m = 0; m < 4; ++m)
#pragma unroll
      for (int n = 0; n < 4; ++n)
        acc[m][n] = mfma16(af[m], bfr[n], acc[m][n]);
  }

#pragma unroll
  for (int n = 0; n < 4; ++n) {
    const int col = n0 + wc * 64 + n * 16 + lc;
    const float bs = bias[col];
#pragma unroll
    for (int m = 0; m < 4; ++m)
#pragma unroll
      for (int r = 0; r < 4; ++r) {
        const int row = m0 + wr * 64 + m * 16 + lg * 4 + r;
        outp[(size_t)row * 1024 + col] = f2bf((acc[m][n][r] + bs) * scale);
      }
  }
}

// ---------- kernel 4: flash attention ----------
// grid (16 qtiles, 64 bh); block 256 = 4 waves; wave w owns q rows [qt*64+16w, +16)
__global__ __launch_bounds__(256) void attn_kernel(
    const unsigned short* __restrict__ Qb,  // (B,S,H,D) bf16, pre-scaled
    const unsigned short* __restrict__ Kb,
    const unsigned short* __restrict__ Vb,
    const int* __restrict__ amask,          // (B,S)
    const float* __restrict__ lhm,          // (H)
    float* __restrict__ out) {              // (B,S,H,D) fp32
  __shared__ alignas(16) char K_lds[64 * 128];    // [key][d] bf16, XOR-swizzled
  __shared__ alignas(16) char Vt_lds[64 * 128];   // [d][key] bf16, XOR-swizzled
  __shared__ alignas(16) char P_lds[4][16 * 128]; // per-wave P tile, swizzled

  const int qt = blockIdx.x;
  const int bh = blockIdx.y;
  const int b = bh >> 4, h = bh & 15;
  const int t = threadIdx.x;
  const int w = t >> 6, l = t & 63;
  const int lg = l >> 4, lc = l & 15;
  const int q0 = qt * 64 + w * 16;

  // Q fragments, hoisted: A row = lc, k = c*32 + lg*8 + e
  const unsigned short* qrow = Qb + (size_t)(b * SEQ + q0 + lc) * HIDD + h * DH;
  const bf16x8 aq0 = *(const bf16x8*)(qrow + lg * 8);
  const bf16x8 aq1 = *(const bf16x8*)(qrow + 32 + lg * 8);

  float m_run[4], l_run[4];
#pragma unroll
  for (int r = 0; r < 4; ++r) { m_run[r] = -INFINITY; l_run[r] = 0.f; }
  f32x4 acc[4] = {};

  for (int k0 = 0; k0 < SEQ; k0 += 64) {
    __syncthreads();
    // ---- stage K (row-major) and V (transposed) into swizzled LDS ----
#pragma unroll
    for (int i = 0; i < 2; ++i) {
      const int cch = i * 256 + t;          // 16B chunk id, 512 total
      const int row = cch >> 3, cp = cch & 7;
      const size_t gbase = (size_t)(b * SEQ + k0 + row) * HIDD + h * DH + cp * 8;
      const uint4 kv = *(const uint4*)(Kb + gbase);
      *(uint4*)(K_lds + ((row * 128 + cp * 16) ^ ((row & 7) << 4))) = kv;
      const uint4 vv = *(const uint4*)(Vb + gbase);
      const unsigned short* pv = (const unsigned short*)&vv;
#pragma unroll
      for (int e = 0; e < 8; ++e) {
        const int d = cp * 8 + e;
        *(unsigned short*)(Vt_lds + ((d * 128 + row * 2) ^ ((d & 7) << 4))) = pv[e];
      }
    }
    __syncthreads();

    // ---- scores: 4 key-subtiles of 16 ----
    f32x4 s[4];
#pragma unroll
    for (int j = 0; j < 4; ++j) {
      const int key = j * 16 + lc;
      const int swz = (key & 7) << 4;
      const bf16x8 b0 = *(const bf16x8*)(K_lds + ((key * 128 + lg * 16) ^ swz));
      const bf16x8 b1 = *(const bf16x8*)(K_lds + ((key * 128 + 64 + lg * 16) ^ swz));
      f32x4 sj = {0.f, 0.f, 0.f, 0.f};
      sj = mfma16(aq0, b0, sj);
      sj = mfma16(aq1, b1, sj);
      const float bias = (amask[b * SEQ + k0 + key] > 0) ? 0.f : -1e30f;
      sj += bias;
      s[j] = sj;
    }

    // ---- online softmax (rows = lg*4 + r, reduce across 16 lanes) ----
    float mx[4];
#pragma unroll
    for (int r = 0; r < 4; ++r)
      mx[r] = fmaxf(fmaxf(s[0][r], s[1][r]), fmaxf(s[2][r], s[3][r]));
#pragma unroll
    for (int off = 1; off < 16; off <<= 1)
#pragma unroll
      for (int r = 0; r < 4; ++r)
        mx[r] = fmaxf(mx[r], __shfl_xor(mx[r], off));

    float sc[4];
#pragma unroll
    for (int r = 0; r < 4; ++r) {
      const float mn = fmaxf(m_run[r], mx[r]);
      sc[r] = __expf(m_run[r] - mn);
      m_run[r] = mn;
    }
    float rs[4] = {0.f, 0.f, 0.f, 0.f};
#pragma unroll
    for (int j = 0; j < 4; ++j)
#pragma unroll
      for (int r = 0; r < 4; ++r) {
        const float p = __expf(s[j][r] - m_run[r]);
        s[j][r] = p;
        rs[r] += p;
      }
#pragma unroll
    for (int off = 1; off < 16; off <<= 1)
#pragma unroll
      for (int r = 0; r < 4; ++r)
        rs[r] += __shfl_xor(rs[r], off);
#pragma unroll
    for (int r = 0; r < 4; ++r)
      l_run[r] = l_run[r] * sc[r] + rs[r];
#pragma unroll
    for (int d = 0; d < 4; ++d)
#pragma unroll
      for (int r = 0; r < 4; ++r)
        acc[d][r] *= sc[r];

    // ---- P (C-layout) -> per-wave LDS (A-layout source), bf16 ----
    char* pl = P_lds[w];
#pragma unroll
    for (int j = 0; j < 4; ++j)
#pragma unroll
      for (int r = 0; r < 4; ++r) {
        const int prow = lg * 4 + r;
        *(unsigned short*)(pl + ((prow * 128 + (j * 16 + lc) * 2) ^
                                 ((prow & 7) << 4))) = f2bf(s[j][r]);
      }

    // ---- PV: acc[d-tile] += P(16x32) x V(32x16) ----
#pragma unroll
    for (int c = 0; c < 2; ++c) {
      const bf16x8 ap = *(const bf16x8*)(pl + ((lc * 128 + c * 64 + lg * 16) ^
                                               ((lc & 7) << 4)));
#pragma unroll
      for (int d = 0; d < 4; ++d) {
        const int vrow = d * 16 + lc;
        const bf16x8 bv8 = *(const bf16x8*)(Vt_lds + ((vrow * 128 + c * 64 + lg * 16) ^
                                                      ((vrow & 7) << 4)));
        acc[d] = mfma16(ap, bv8, acc[d]);
      }
    }
  }

  // ---- epilogue: normalize, head-mask, write fp32 ----
  const float hm = lhm[h];
  float inv[4];
#pragma unroll
  for (int r = 0; r < 4; ++r) inv[r] = hm / l_run[r];
#pragma unroll
  for (int d = 0; d < 4; ++d)
#pragma unroll
    for (int r = 0; r < 4; ++r) {
      const int row = q0 + lg * 4 + r;
      out[(size_t)(b * SEQ + row) * HIDD + h * DH + d * 16 + lc] =
          acc[d][r] * inv[r];
    }
}

// ---------- launch ----------
extern "C" void kernel_launch(void* const* d_in, const int* in_sizes, int n_in,
                              void* d_out, int out_size, void* d_ws, size_t ws_size,
                              hipStream_t stream) {
  const float* hs = (const float*)d_in[0];
  const int* amask = (const int*)d_in[1];
  const float* lhm = (const float*)d_in[2];
  const float* Wq = (const float*)d_in[3];
  const float* bq = (const float*)d_in[4];
  const float* Wk = (const float*)d_in[5];
  const float* bk = (const float*)d_in[6];
  const float* Wv = (const float*)d_in[7];
  const float* bv = (const float*)d_in[8];
  float* out = (float*)d_out;

  char* ws = (char*)d_ws;
  unsigned short* HSbf = (unsigned short*)ws;                   // 8 MB
  unsigned short* Wt = (unsigned short*)(ws + (8u << 20));      // 6 MB
  unsigned short* QKV = (unsigned short*)(ws + (14u << 20));    // 24 MB

  hs2bf<<<4096, 256, 0, stream>>>(hs, HSbf);
  wtrans<<<dim3(16, 16, 3), 256, 0, stream>>>(Wq, Wk, Wv, Wt);
  qkv_gemm<<<dim3(32, 8, 3), 256, 0, stream>>>(HSbf, Wt, bq, bk, bv, QKV);
  attn_kernel<<<dim3(16, 64), 256, 0, stream>>>(
      QKV, QKV + (size_t)4096 * 1024, QKV + (size_t)2 * 4096 * 1024,
      amask, lhm, out);
}

// Round 2
// 125.676 us; speedup vs baseline: 1.0604x; 1.0604x over previous
//
#include <hip/hip_runtime.h>
#include <stdint.h>

typedef __bf16 bf16_t;
typedef bf16_t __attribute__((ext_vector_type(8))) bf16x8;
typedef float __attribute__((ext_vector_type(4))) f32x4;

#define BATCH 4
#define SEQ 1024
#define HIDD 1024
#define NH 16
#define DH 64

// ---------- helpers ----------
__device__ __forceinline__ unsigned short f2bf(float f) {
  unsigned u = __float_as_uint(f);
  u += 0x7fffu + ((u >> 16) & 1u);   // RNE (no NaN handling needed here)
  return (unsigned short)(u >> 16);
}

__device__ __forceinline__ f32x4 mfma16(bf16x8 a, bf16x8 b, f32x4 c) {
  return __builtin_amdgcn_mfma_f32_16x16x32_bf16(a, b, c, 0, 0, 0);
}

__device__ __forceinline__ void gload_lds16(const void* g, void* l) {
  __builtin_amdgcn_global_load_lds(
      (__attribute__((address_space(1))) void*)(uintptr_t)g,
      (__attribute__((address_space(3))) void*)l, 16, 0, 0);
}

// ---------- kernel 1: hidden_states fp32 -> bf16 ----------
__global__ void hs2bf(const float* __restrict__ x, unsigned short* __restrict__ y) {
  const int i = blockIdx.x * 256 + threadIdx.x;   // 1M float4s total
  const float4 f = ((const float4*)x)[i];
  ushort4 o = make_ushort4(f2bf(f.x), f2bf(f.y), f2bf(f.z), f2bf(f.w));
  ((ushort4*)y)[i] = o;
}

// ---------- kernel 2: W (K x N) fp32 -> Wt (N x K) bf16, for q/k/v ----------
__global__ __launch_bounds__(256) void wtrans(
    const float* __restrict__ Wq, const float* __restrict__ Wk,
    const float* __restrict__ Wv, unsigned short* __restrict__ Wt) {
  __shared__ unsigned short tile[64][72];  // +8 pad
  const int z = blockIdx.z;
  const float* W = (z == 0) ? Wq : (z == 1) ? Wk : Wv;
  unsigned short* o = Wt + (size_t)z * (1024 * 1024);
  const int k0 = blockIdx.x * 64, n0 = blockIdx.y * 64;
  const int r = threadIdx.x >> 6, c = threadIdx.x & 63;
#pragma unroll
  for (int i = 0; i < 16; ++i) {
    const int row = i * 4 + r;
    tile[row][c] = f2bf(W[(size_t)(k0 + row) * 1024 + n0 + c]);
  }
  __syncthreads();
#pragma unroll
  for (int i = 0; i < 16; ++i) {
    const int row = i * 4 + r;                 // row in n
    o[(size_t)(n0 + row) * 1024 + k0 + c] = tile[c][row];
  }
}

// ---------- kernel 3: QKV projection GEMM (m97-style gemm_bt) ----------
// C[m][n] = sum_k A[m][k] * Bt[n][k]; out = (C + bias) * scale, bf16.
// Q gets scale = log2(e)/sqrt(D) so attention works in exp2 domain.
__global__ __launch_bounds__(256) void qkv_gemm(
    const unsigned short* __restrict__ A,    // 4096 x 1024 bf16
    const unsigned short* __restrict__ Wt,   // 3 x (1024 x 1024) bf16, n-major
    const float* __restrict__ bq, const float* __restrict__ bk,
    const float* __restrict__ bv,
    unsigned short* __restrict__ outb) {     // 3 x (4096 x 1024) bf16
  __shared__ alignas(16) unsigned short Alds[128 * 32];
  __shared__ alignas(16) unsigned short Blds[128 * 32];

  const int z = blockIdx.z;
  const unsigned short* Bt = Wt + (size_t)z * (1024 * 1024);
  const float* bias = (z == 0) ? bq : (z == 1) ? bk : bv;
  unsigned short* outp = outb + (size_t)z * (4096 * 1024);
  const float scale = (z == 0) ? 0.125f * 1.44269504089f : 1.0f;

  const int m0 = blockIdx.x * 128;
  const int n0 = blockIdx.y * 128;
  const int t = threadIdx.x;
  const int w = t >> 6, l = t & 63;
  const int lg = l >> 4, lc = l & 15;
  const int wr = w >> 1, wc = w & 1;

  f32x4 acc[4][4] = {};

  for (int kt = 0; kt < 1024; kt += 32) {
    __syncthreads();
#pragma unroll
    for (int i = 0; i < 2; ++i) {
      const int c = i * 256 + t;          // 16B chunk id, 512 per tile
      const int row = c >> 2;
      const int kp = (c & 3) * 8;
      gload_lds16(A + (size_t)(m0 + row) * 1024 + kt + kp,
                  (char*)Alds + i * 4096 + w * 1024);
      gload_lds16(Bt + (size_t)(n0 + row) * 1024 + kt + kp,
                  (char*)Blds + i * 4096 + w * 1024);
    }
    __syncthreads();

    bf16x8 af[4], bfr[4];
#pragma unroll
    for (int m = 0; m < 4; ++m)
      af[m] = *(const bf16x8*)(Alds + (wr * 64 + m * 16 + lc) * 32 + lg * 8);
#pragma unroll
    for (int n = 0; n < 4; ++n)
      bfr[n] = *(const bf16x8*)(Blds + (wc * 64 + n * 16 + lc) * 32 + lg * 8);
#pragma unroll
    for (int m = 0; m < 4; ++m)
#pragma unroll
      for (int n = 0; n < 4; ++n)
        acc[m][n] = mfma16(af[m], bfr[n], acc[m][n]);
  }

#pragma unroll
  for (int n = 0; n < 4; ++n) {
    const int col = n0 + wc * 64 + n * 16 + lc;
    const float bs = bias[col];
#pragma unroll
    for (int m = 0; m < 4; ++m)
#pragma unroll
      for (int r = 0; r < 4; ++r) {
        const int row = m0 + wr * 64 + m * 16 + lg * 4 + r;
        outp[(size_t)row * 1024 + col] = f2bf((acc[m][n][r] + bs) * scale);
      }
  }
}

// ---------- kernel 3.5: V (4096 x 1024) bf16 -> Vt (B,H,D,S) bf16 ----------
__global__ __launch_bounds__(256) void vtrans(
    const unsigned short* __restrict__ V, unsigned short* __restrict__ Vt) {
  __shared__ unsigned short tile[64][72];  // +8 pad
  const int tt = blockIdx.x;   // token tile (64 tokens)
  const int hh = blockIdx.y;   // head
  const int t = threadIdx.x;
#pragma unroll
  for (int i = 0; i < 2; ++i) {
    const int c = i * 256 + t;            // 512 chunks of 16B
    const int row = c >> 3, cp = c & 7;
    *(uint4*)&tile[row][cp * 8] =
        *(const uint4*)(V + (size_t)(tt * 64 + row) * 1024 + hh * 64 + cp * 8);
  }
  __syncthreads();
  const int b = (tt * 64) >> 10, s0 = (tt * 64) & 1023;
  const int d = t >> 2, toff = (t & 3) * 16;
  unsigned short buf[16];
#pragma unroll
  for (int e = 0; e < 16; ++e) buf[e] = tile[toff + e][d];
  unsigned short* dst = Vt + ((size_t)(b * NH + hh) * DH + d) * SEQ + s0 + toff;
  *(uint4*)dst = *(uint4*)buf;
  *(uint4*)(dst + 8) = *(uint4*)(buf + 8);
}

// ---------- kernel 4: flash attention (double-buffered, gload_lds staging) ----------
// grid 1024 (XCD-swizzled -> qt, bh); block 256 = 4 waves; wave w: q rows [qt*64+16w, +16)
__global__ __launch_bounds__(256) void attn_kernel(
    const unsigned short* __restrict__ Qb,  // (B,S,H,D) bf16, pre-scaled by log2e/sqrt(D)
    const unsigned short* __restrict__ Kb,  // (B,S,H,D) bf16
    const unsigned short* __restrict__ Vt,  // (B,H,D,S) bf16
    const int* __restrict__ amask,          // (B,S)
    const float* __restrict__ lhm,          // (H)
    float* __restrict__ out) {              // (B,S,H,D) fp32
  __shared__ alignas(16) char K_lds[2 * 8192];   // [buf][key][d], XOR-swizzled
  __shared__ alignas(16) char V_lds[2 * 8192];   // [buf][d][key], XOR-swizzled
  __shared__ alignas(16) char P_lds[4][2048];    // per-wave P tile, swizzled

  const int id = blockIdx.x;
  const int swzid = (id & 7) * 128 + (id >> 3);  // XCD-bijective: 8 heads per XCD
  const int qt = swzid & 15;
  const int bh = swzid >> 4;
  const int b = bh >> 4, h = bh & 15;
  const int t = threadIdx.x;
  const int w = t >> 6, l = t & 63;
  const int lg = l >> 4, lc = l & 15;
  const int q0 = qt * 64 + w * 16;

  // staging geometry (per wave: 2 calls x 1KB for each of K and Vt)
  const int c0 = w * 128 + l;              // base chunk id for i=0
  const unsigned short* Kbase = Kb + (size_t)b * SEQ * HIDD + h * DH;
  const unsigned short* Vtbase = Vt + (size_t)bh * DH * SEQ;

  // Q fragments, hoisted: A row = lc, k = c*32 + lg*8 + e
  const unsigned short* qrow = Qb + (size_t)(b * SEQ + q0 + lc) * HIDD + h * DH;
  const bf16x8 aq0 = *(const bf16x8*)(qrow + lg * 8);
  const bf16x8 aq1 = *(const bf16x8*)(qrow + 32 + lg * 8);

  float m_run[4], l_run[4];
#pragma unroll
  for (int r = 0; r < 4; ++r) { m_run[r] = -INFINITY; l_run[r] = 0.f; }
  f32x4 acc[4] = {};

  // ---- stage tile k0 into buffer `buf` (linear LDS dest, pre-swizzled src) ----
  auto stage = [&](int k0, int buf) {
    char* kb = K_lds + buf * 8192 + w * 2048;
    char* vb = V_lds + buf * 8192 + w * 2048;
#pragma unroll
    for (int i = 0; i < 2; ++i) {
      const int c = c0 + i * 64;
      const int row = c >> 3;
      const int cps = (c & 7) ^ (row & 7);          // inverse-swizzled src chunk
      gload_lds16(Kbase + (size_t)(k0 + row) * HIDD + cps * 8, kb + i * 1024);
      gload_lds16(Vtbase + (size_t)row * SEQ + k0 + cps * 8, vb + i * 1024);
    }
  };

  stage(0, 0);
  __syncthreads();

  for (int tk = 0; tk < 16; ++tk) {
    const int cur = tk & 1;
    const int k0 = tk * 64;
    if (tk < 15) stage(k0 + 64, cur ^ 1);

    const char* kb = K_lds + cur * 8192;
    const char* vb = V_lds + cur * 8192;

    // ---- scores: 4 key-subtiles of 16 (exp2 domain; Q pre-scaled) ----
    f32x4 s[4];
#pragma unroll
    for (int j = 0; j < 4; ++j) {
      const int key = j * 16 + lc;
      const int swz = (key & 7) << 4;
      const bf16x8 b0 = *(const bf16x8*)(kb + key * 128 + ((lg * 16) ^ swz));
      const bf16x8 b1 = *(const bf16x8*)(kb + key * 128 + ((64 + lg * 16) ^ swz));
      f32x4 sj = {0.f, 0.f, 0.f, 0.f};
      sj = mfma16(aq0, b0, sj);
      sj = mfma16(aq1, b1, sj);
      const float bias = (amask[b * SEQ + k0 + key] > 0) ? 0.f : -1e30f;
      sj += bias;
      s[j] = sj;
    }

    // ---- online softmax (rows = lg*4 + r, reduce across 16 lanes) ----
    float mx[4];
#pragma unroll
    for (int r = 0; r < 4; ++r)
      mx[r] = fmaxf(fmaxf(s[0][r], s[1][r]), fmaxf(s[2][r], s[3][r]));
#pragma unroll
    for (int off = 1; off < 16; off <<= 1)
#pragma unroll
      for (int r = 0; r < 4; ++r)
        mx[r] = fmaxf(mx[r], __shfl_xor(mx[r], off));

    float sc[4];
#pragma unroll
    for (int r = 0; r < 4; ++r) {
      const float mn = fmaxf(m_run[r], mx[r]);
      sc[r] = exp2f(m_run[r] - mn);
      m_run[r] = mn;
    }
    float rs[4] = {0.f, 0.f, 0.f, 0.f};
#pragma unroll
    for (int j = 0; j < 4; ++j)
#pragma unroll
      for (int r = 0; r < 4; ++r) {
        const float p = exp2f(s[j][r] - m_run[r]);
        s[j][r] = p;
        rs[r] += p;
      }
#pragma unroll
    for (int off = 1; off < 16; off <<= 1)
#pragma unroll
      for (int r = 0; r < 4; ++r)
        rs[r] += __shfl_xor(rs[r], off);
#pragma unroll
    for (int r = 0; r < 4; ++r)
      l_run[r] = l_run[r] * sc[r] + rs[r];
#pragma unroll
    for (int d = 0; d < 4; ++d)
#pragma unroll
      for (int r = 0; r < 4; ++r)
        acc[d][r] *= sc[r];

    // ---- P (C-layout) -> per-wave LDS (A-layout source), bf16 ----
    char* pl = P_lds[w];
#pragma unroll
    for (int j = 0; j < 4; ++j)
#pragma unroll
      for (int r = 0; r < 4; ++r) {
        const int prow = lg * 4 + r;
        *(unsigned short*)(pl + ((prow * 128 + (j * 16 + lc) * 2) ^
                                 ((prow & 7) << 4))) = f2bf(s[j][r]);
      }

    // ---- PV: acc[d-tile] += P(16x32) x V(32x16) ----
#pragma unroll
    for (int c = 0; c < 2; ++c) {
      const bf16x8 ap = *(const bf16x8*)(pl + ((lc * 128 + c * 64 + lg * 16) ^
                                               ((lc & 7) << 4)));
#pragma unroll
      for (int d = 0; d < 4; ++d) {
        const int vrow = d * 16 + lc;
        const bf16x8 bv8 = *(const bf16x8*)(vb + ((vrow * 128 + c * 64 + lg * 16) ^
                                                  ((vrow & 7) << 4)));
        acc[d] = mfma16(ap, bv8, acc[d]);
      }
    }

    __syncthreads();   // drains vmcnt (next tile staged) + protects buffer reuse
  }

  // ---- epilogue: normalize, head-mask, write fp32 ----
  const float hm = lhm[h];
  float inv[4];
#pragma unroll
  for (int r = 0; r < 4; ++r) inv[r] = hm / l_run[r];
#pragma unroll
  for (int d = 0; d < 4; ++d)
#pragma unroll
    for (int r = 0; r < 4; ++r) {
      const int row = q0 + lg * 4 + r;
      out[(size_t)(b * SEQ + row) * HIDD + h * DH + d * 16 + lc] =
          acc[d][r] * inv[r];
    }
}

// ---------- launch ----------
extern "C" void kernel_launch(void* const* d_in, const int* in_sizes, int n_in,
                              void* d_out, int out_size, void* d_ws, size_t ws_size,
                              hipStream_t stream) {
  const float* hs = (const float*)d_in[0];
  const int* amask = (const int*)d_in[1];
  const float* lhm = (const float*)d_in[2];
  const float* Wq = (const float*)d_in[3];
  const float* bq = (const float*)d_in[4];
  const float* Wk = (const float*)d_in[5];
  const float* bk = (const float*)d_in[6];
  const float* Wv = (const float*)d_in[7];
  const float* bv = (const float*)d_in[8];
  float* out = (float*)d_out;

  char* ws = (char*)d_ws;
  unsigned short* HSbf = (unsigned short*)ws;                   // 8 MB
  unsigned short* Wt = (unsigned short*)(ws + (8u << 20));      // 6 MB
  unsigned short* QKV = (unsigned short*)(ws + (14u << 20));    // 24 MB
  unsigned short* Vtr = (unsigned short*)(ws + (38u << 20));    // 8 MB

  hs2bf<<<4096, 256, 0, stream>>>(hs, HSbf);
  wtrans<<<dim3(16, 16, 3), 256, 0, stream>>>(Wq, Wk, Wv, Wt);
  qkv_gemm<<<dim3(32, 8, 3), 256, 0, stream>>>(HSbf, Wt, bq, bk, bv, QKV);
  vtrans<<<dim3(64, 16), 256, 0, stream>>>(QKV + (size_t)2 * 4096 * 1024, Vtr);
  attn_kernel<<<1024, 256, 0, stream>>>(
      QKV, QKV + (size_t)4096 * 1024, Vtr, amask, lhm, out);
}

// Round 3
// 106.068 us; speedup vs baseline: 1.2564x; 1.1849x over previous
//
#include <hip/hip_runtime.h>
#include <stdint.h>

typedef __bf16 bf16_t;
typedef bf16_t __attribute__((ext_vector_type(8))) bf16x8;
typedef float __attribute__((ext_vector_type(4))) f32x4;
typedef float __attribute__((ext_vector_type(16))) f32x16;
typedef unsigned u32;

#define BATCH 4
#define SEQ 1024
#define HIDD 1024
#define NH 16
#define DH 64

// ---------- helpers ----------
__device__ __forceinline__ unsigned short f2bf(float f) {
  unsigned u = __float_as_uint(f);
  u += 0x7fffu + ((u >> 16) & 1u);   // RNE
  return (unsigned short)(u >> 16);
}

__device__ __forceinline__ f32x4 mfma16(bf16x8 a, bf16x8 b, f32x4 c) {
  return __builtin_amdgcn_mfma_f32_16x16x32_bf16(a, b, c, 0, 0, 0);
}
__device__ __forceinline__ f32x16 mfma32(bf16x8 a, bf16x8 b, f32x16 c) {
  return __builtin_amdgcn_mfma_f32_32x32x16_bf16(a, b, c, 0, 0, 0);
}

__device__ __forceinline__ void gload_lds16(const void* g, void* l) {
  __builtin_amdgcn_global_load_lds(
      (__attribute__((address_space(1))) void*)(uintptr_t)g,
      (__attribute__((address_space(3))) void*)l, 16, 0, 0);
}

__device__ __forceinline__ u32 cvtpk(float lo, float hi) {
  u32 r;
  asm("v_cvt_pk_bf16_f32 %0, %1, %2" : "=v"(r) : "v"(lo), "v"(hi));
  return r;
}
__device__ __forceinline__ void plswap(u32& a, u32& b) {
  // vdst(a) lanes>=32 <-> vsrc(b) lanes<32
  asm("v_permlane32_swap_b32 %0, %1" : "+v"(a), "+v"(b));
}

// ---------- kernel 1: hidden_states fp32 -> bf16 ----------
__global__ void hs2bf(const float* __restrict__ x, unsigned short* __restrict__ y) {
  const int i = blockIdx.x * 256 + threadIdx.x;
  const float4 f = ((const float4*)x)[i];
  ushort4 o = make_ushort4(f2bf(f.x), f2bf(f.y), f2bf(f.z), f2bf(f.w));
  ((ushort4*)y)[i] = o;
}

// ---------- kernel 2: W (K x N) fp32 -> Wt (N x K) bf16 ----------
__global__ __launch_bounds__(256) void wtrans(
    const float* __restrict__ Wq, const float* __restrict__ Wk,
    const float* __restrict__ Wv, unsigned short* __restrict__ Wt) {
  __shared__ unsigned short tile[64][72];
  const int z = blockIdx.z;
  const float* W = (z == 0) ? Wq : (z == 1) ? Wk : Wv;
  unsigned short* o = Wt + (size_t)z * (1024 * 1024);
  const int k0 = blockIdx.x * 64, n0 = blockIdx.y * 64;
  const int r = threadIdx.x >> 6, c = threadIdx.x & 63;
#pragma unroll
  for (int i = 0; i < 16; ++i) {
    const int row = i * 4 + r;
    tile[row][c] = f2bf(W[(size_t)(k0 + row) * 1024 + n0 + c]);
  }
  __syncthreads();
#pragma unroll
  for (int i = 0; i < 16; ++i) {
    const int row = i * 4 + r;
    o[(size_t)(n0 + row) * 1024 + k0 + c] = tile[c][row];
  }
}

// ---------- kernel 3: QKV projection GEMM ----------
__global__ __launch_bounds__(256) void qkv_gemm(
    const unsigned short* __restrict__ A,
    const unsigned short* __restrict__ Wt,
    const float* __restrict__ bq, const float* __restrict__ bk,
    const float* __restrict__ bv,
    unsigned short* __restrict__ outb) {
  __shared__ alignas(16) unsigned short Alds[128 * 32];
  __shared__ alignas(16) unsigned short Blds[128 * 32];

  const int z = blockIdx.z;
  const unsigned short* Bt = Wt + (size_t)z * (1024 * 1024);
  const float* bias = (z == 0) ? bq : (z == 1) ? bk : bv;
  unsigned short* outp = outb + (size_t)z * (4096 * 1024);
  const float scale = (z == 0) ? 0.125f * 1.44269504089f : 1.0f; // exp2 domain for Q

  const int m0 = blockIdx.x * 128;
  const int n0 = blockIdx.y * 128;
  const int t = threadIdx.x;
  const int w = t >> 6, l = t & 63;
  const int lg = l >> 4, lc = l & 15;
  const int wr = w >> 1, wc = w & 1;

  f32x4 acc[4][4] = {};

  for (int kt = 0; kt < 1024; kt += 32) {
    __syncthreads();
#pragma unroll
    for (int i = 0; i < 2; ++i) {
      const int c = i * 256 + t;
      const int row = c >> 2;
      const int kp = (c & 3) * 8;
      gload_lds16(A + (size_t)(m0 + row) * 1024 + kt + kp,
                  (char*)Alds + i * 4096 + w * 1024);
      gload_lds16(Bt + (size_t)(n0 + row) * 1024 + kt + kp,
                  (char*)Blds + i * 4096 + w * 1024);
    }
    __syncthreads();

    bf16x8 af[4], bfr[4];
#pragma unroll
    for (int m = 0; m < 4; ++m)
      af[m] = *(const bf16x8*)(Alds + (wr * 64 + m * 16 + lc) * 32 + lg * 8);
#pragma unroll
    for (int n = 0; n < 4; ++n)
      bfr[n] = *(const bf16x8*)(Blds + (wc * 64 + n * 16 + lc) * 32 + lg * 8);
#pragma unroll
    for (int m = 0; m < 4; ++m)
#pragma unroll
      for (int n = 0; n < 4; ++n)
        acc[m][n] = mfma16(af[m], bfr[n], acc[m][n]);
  }

#pragma unroll
  for (int n = 0; n < 4; ++n) {
    const int col = n0 + wc * 64 + n * 16 + lc;
    const float bs = bias[col];
#pragma unroll
    for (int m = 0; m < 4; ++m)
#pragma unroll
      for (int r = 0; r < 4; ++r) {
        const int row = m0 + wr * 64 + m * 16 + lg * 4 + r;
        outp[(size_t)row * 1024 + col] = f2bf((acc[m][n][r] + bs) * scale);
      }
  }
}

// ---------- kernel 3.5: V -> Vt (B,H,D,S) ----------
__global__ __launch_bounds__(256) void vtrans(
    const unsigned short* __restrict__ V, unsigned short* __restrict__ Vt) {
  __shared__ unsigned short tile[64][72];
  const int tt = blockIdx.x;
  const int hh = blockIdx.y;
  const int t = threadIdx.x;
#pragma unroll
  for (int i = 0; i < 2; ++i) {
    const int c = i * 256 + t;
    const int row = c >> 3, cp = c & 7;
    *(uint4*)&tile[row][cp * 8] =
        *(const uint4*)(V + (size_t)(tt * 64 + row) * 1024 + hh * 64 + cp * 8);
  }
  __syncthreads();
  const int b = (tt * 64) >> 10, s0 = (tt * 64) & 1023;
  const int d = t >> 2, toff = (t & 3) * 16;
  unsigned short buf[16];
#pragma unroll
  for (int e = 0; e < 16; ++e) buf[e] = tile[toff + e][d];
  unsigned short* dst = Vt + ((size_t)(b * NH + hh) * DH + d) * SEQ + s0 + toff;
  *(uint4*)dst = *(uint4*)buf;
  *(uint4*)(dst + 8) = *(uint4*)(buf + 8);
}

// ---------- kernel 4: flash attention, 32x32 swapped-QK^T, in-register P ----------
// grid 512 (XCD-swizzled -> 8 qt x 64 bh); block 256 = 4 waves x 32 q-rows.
// LDS K/V tiles: pair-rows [r=idx>>1][256B = (idx&1)*128 + other*2], XOR ^((r&15)<<4).
// S^T = mfma32(K, Q^T): C col=lane&31=qrow, row=key=(reg&3)+8*(reg>>2)+4*(lane>>5).
__global__ __launch_bounds__(256) void attn_kernel(
    const unsigned short* __restrict__ Qb,  // (B,S,H,D) bf16, pre-scaled log2e/sqrt(D)
    const unsigned short* __restrict__ Kb,  // (B,S,H,D) bf16
    const unsigned short* __restrict__ Vt,  // (B,H,D,S) bf16
    const int* __restrict__ amask,          // (B,S)
    const float* __restrict__ lhm,          // (H)
    float* __restrict__ out) {              // (B,S,HID) fp32
  __shared__ alignas(16) char K_lds[2][8192];
  __shared__ alignas(16) char V_lds[2][8192];

  const int id = blockIdx.x;
  const int swzid = (id & 7) * 64 + (id >> 3);  // 8 bh per XCD
  const int qt = swzid & 7;
  const int bh = swzid >> 3;
  const int b = bh >> 4, h = bh & 15;
  const int t = threadIdx.x;
  const int w = t >> 6, l = t & 63;
  const int lo = l & 31, hi = l >> 5;
  const int q0 = qt * 128 + w * 32;

  const unsigned short* Kbase = Kb + (size_t)b * SEQ * HIDD + h * DH;
  const unsigned short* Vtbase = Vt + (size_t)bh * DH * SEQ;

  // staging: chunk c = i*256+t; r=c>>4, slot=c&15, u=slot^(r&15) -> {half,sub}
  const int r0 = t >> 4;
  const int uu = (t & 15) ^ (r0 & 15);
  const unsigned short* ksrc = Kbase + (size_t)(2 * r0 + (uu >> 3)) * HIDD + (uu & 7) * 8;
  const unsigned short* vsrc = Vtbase + (size_t)(2 * r0 + (uu >> 3)) * SEQ + (uu & 7) * 8;

  // Q fragments (B-operand): lane holds Q[q0+lo][d = s*16 + hi*8 + e]
  const unsigned short* qp = Qb + (size_t)(b * SEQ + q0 + lo) * HIDD + h * DH + hi * 8;
  bf16x8 qf[4];
#pragma unroll
  for (int s = 0; s < 4; ++s) qf[s] = *(const bf16x8*)(qp + s * 16);

  float m_run = -INFINITY, l_run = 0.f;
  f32x16 acc0 = {}, acc1 = {};

  // LDS read address: g*4096 + (lo>>1)*256 + ((ib + s*32) ^ swz)
  const int rbase = (lo >> 1) * 256;
  const int swz = (lo >> 1) << 4;
  const int ib = (lo & 1) * 128 + hi * 16;

  auto stage = [&](int k0, int buf) {
    char* kb = &K_lds[buf][w * 1024];
    char* vb = &V_lds[buf][w * 1024];
    gload_lds16(ksrc + (size_t)k0 * HIDD, kb);
    gload_lds16(ksrc + (size_t)(k0 + 32) * HIDD, kb + 4096);
    gload_lds16(vsrc + k0, vb);
    gload_lds16(vsrc + 32 * SEQ + k0, vb + 4096);
  };

  stage(0, 0);
  __syncthreads();

  for (int tk = 0; tk < 16; ++tk) {
    const int cur = tk & 1;
    const int k0 = tk * 64;
    if (tk < 15) stage(k0 + 64, cur ^ 1);

    const char* kb = K_lds[cur];
    const char* vb = V_lds[cur];

    const int mv = amask[b * SEQ + k0 + l];
    const unsigned long long m64 = __ballot(mv > 0);

    // ---- S^T = K · Q^T (two 32-key groups) ----
    f32x16 sg0 = {}, sg1 = {};
    __builtin_amdgcn_s_setprio(1);
#pragma unroll
    for (int s = 0; s < 4; ++s) {
      const int off = rbase + ((ib + s * 32) ^ swz);
      const bf16x8 ka0 = *(const bf16x8*)(kb + off);
      const bf16x8 ka1 = *(const bf16x8*)(kb + 4096 + off);
      sg0 = mfma32(ka0, qf[s], sg0);
      sg1 = mfma32(ka1, qf[s], sg1);
    }
    __builtin_amdgcn_s_setprio(0);

    // ---- row max: in-lane tree over 32 + one cross-half exchange ----
    float t0[8];
#pragma unroll
    for (int i = 0; i < 8; ++i)
      t0[i] = fmaxf(fmaxf(sg0[i], sg0[i + 8]), fmaxf(sg1[i], sg1[i + 8]));
    float t1 = fmaxf(fmaxf(fmaxf(t0[0], t0[1]), fmaxf(t0[2], t0[3])),
                     fmaxf(fmaxf(t0[4], t0[5]), fmaxf(t0[6], t0[7])));
    const float pmax = fmaxf(t1, __shfl_xor(t1, 32));

    // ---- defer-max (T13): rescale only when max grew past THR=8 ----
    if (!__all(pmax <= m_run + 8.f)) {
      const float mnew = fmaxf(m_run, pmax);
      const float sc = __builtin_amdgcn_exp2f(m_run - mnew);
      m_run = mnew;
      l_run *= sc;
#pragma unroll
      for (int g = 0; g < 16; ++g) {
        const int rowi = (g & 3) + 8 * (g >> 2) + 4 * hi;
        const float scr = __shfl(sc, rowi);
        acc0[g] *= scr;
        acc1[g] *= scr;
      }
    }

    // ---- p = exp2(s - m) ----
#pragma unroll
    for (int g = 0; g < 16; ++g) {
      sg0[g] = __builtin_amdgcn_exp2f(sg0[g] - m_run);
      sg1[g] = __builtin_amdgcn_exp2f(sg1[g] - m_run);
    }

    // ---- mask (post-exp multiplicative; softmax invariant to max ref) ----
    if (m64 != ~0ull) {
#pragma unroll
      for (int g = 0; g < 16; ++g) {
        const int krow = (g & 3) + 8 * (g >> 2) + 4 * hi;
        if (!((m64 >> krow) & 1)) sg0[g] = 0.f;
        if (!((m64 >> (krow + 32)) & 1)) sg1[g] = 0.f;
      }
    }

    // ---- row sum ----
    float s0[8];
#pragma unroll
    for (int i = 0; i < 8; ++i)
      s0[i] = (sg0[i] + sg0[i + 8]) + (sg1[i] + sg1[i + 8]);
    float rs = ((s0[0] + s0[1]) + (s0[2] + s0[3])) +
               ((s0[4] + s0[5]) + (s0[6] + s0[7]));
    rs += __shfl_xor(rs, 32);
    l_run += rs;

    // ---- P -> bf16 PA fragments in-register (T12) ----
    auto mk = [](float a0, float a1, float a2, float a3,
                 float a4, float a5, float a6, float a7) -> bf16x8 {
      u32 x = cvtpk(a0, a1), y = cvtpk(a2, a3);
      u32 a = cvtpk(a4, a5), b2 = cvtpk(a6, a7);
      plswap(x, a);   // x: keys(0,1|8,9)   a: keys(4,5|12,13)
      plswap(y, b2);  // y: keys(2,3|10,11) b2: keys(6,7|14,15)
      union { u32 u[4]; bf16x8 v; } fu;
      fu.u[0] = x; fu.u[1] = y; fu.u[2] = a; fu.u[3] = b2;
      return fu.v;
    };
    const bf16x8 pa0 = mk(sg0[0], sg0[1], sg0[2], sg0[3], sg0[4], sg0[5], sg0[6], sg0[7]);
    const bf16x8 pa1 = mk(sg0[8], sg0[9], sg0[10], sg0[11], sg0[12], sg0[13], sg0[14], sg0[15]);
    const bf16x8 pa2 = mk(sg1[0], sg1[1], sg1[2], sg1[3], sg1[4], sg1[5], sg1[6], sg1[7]);
    const bf16x8 pa3 = mk(sg1[8], sg1[9], sg1[10], sg1[11], sg1[12], sg1[13], sg1[14], sg1[15]);

    // ---- PV: acc[dt] += P · V ----
    __builtin_amdgcn_s_setprio(1);
#pragma unroll
    for (int s = 0; s < 4; ++s) {
      const bf16x8 paf = (s == 0) ? pa0 : (s == 1) ? pa1 : (s == 2) ? pa2 : pa3;
      const int off = rbase + ((ib + s * 32) ^ swz);
      const bf16x8 v0 = *(const bf16x8*)(vb + off);
      const bf16x8 v1 = *(const bf16x8*)(vb + 4096 + off);
      acc0 = mfma32(paf, v0, acc0);
      acc1 = mfma32(paf, v1, acc1);
    }
    __builtin_amdgcn_s_setprio(0);

    __syncthreads();
  }

  // ---- epilogue ----
  const float hm = lhm[h];
  const float inv = hm / l_run;   // valid on lane 'lo' (both halves)
  float* ob = out + (size_t)(b * SEQ + q0) * HIDD + h * DH + lo;
#pragma unroll
  for (int g = 0; g < 16; ++g) {
    const int rowi = (g & 3) + 8 * (g >> 2) + 4 * hi;
    const float iv = __shfl(inv, rowi);
    ob[(size_t)rowi * HIDD] = acc0[g] * iv;
    ob[(size_t)rowi * HIDD + 32] = acc1[g] * iv;
  }
}

// ---------- launch ----------
extern "C" void kernel_launch(void* const* d_in, const int* in_sizes, int n_in,
                              void* d_out, int out_size, void* d_ws, size_t ws_size,
                              hipStream_t stream) {
  const float* hs = (const float*)d_in[0];
  const int* amask = (const int*)d_in[1];
  const float* lhm = (const float*)d_in[2];
  const float* Wq = (const float*)d_in[3];
  const float* bq = (const float*)d_in[4];
  const float* Wk = (const float*)d_in[5];
  const float* bk = (const float*)d_in[6];
  const float* Wv = (const float*)d_in[7];
  const float* bv = (const float*)d_in[8];
  float* out = (float*)d_out;

  char* ws = (char*)d_ws;
  unsigned short* HSbf = (unsigned short*)ws;                   // 8 MB
  unsigned short* Wt = (unsigned short*)(ws + (8u << 20));      // 6 MB
  unsigned short* QKV = (unsigned short*)(ws + (14u << 20));    // 24 MB
  unsigned short* Vtr = (unsigned short*)(ws + (38u << 20));    // 8 MB

  hs2bf<<<4096, 256, 0, stream>>>(hs, HSbf);
  wtrans<<<dim3(16, 16, 3), 256, 0, stream>>>(Wq, Wk, Wv, Wt);
  qkv_gemm<<<dim3(32, 8, 3), 256, 0, stream>>>(HSbf, Wt, bq, bk, bv, QKV);
  vtrans<<<dim3(64, 16), 256, 0, stream>>>(QKV + (size_t)2 * 4096 * 1024, Vtr);
  attn_kernel<<<512, 256, 0, stream>>>(
      QKV, QKV + (size_t)4096 * 1024, Vtr, amask, lhm, out);
}